// Round 15
// baseline (555.667 us; speedup 1.0000x reference)
//
#include <hip/hip_runtime.h>
#include <hip/hip_bf16.h>
#include <cstdint>
#include <cstddef>

// ---------------------------------------------------------------------------
// GATWithSkip: 3x GATConv + BN/ELU/skips on MI355X.
// R14 (442us): vectorized bn_stats (the hidden 100us), R10 aggregate/GEMM/CSR.
// R15: scalar-uniform csr loads in aggregate (readfirstlane -> saddr gather);
//      GEMM grids 1024; bn_apply ushort8; scan_tops folded into scan_add.
// ---------------------------------------------------------------------------

#define LRELU_SLOPE 0.2f
#define NSTATB 256   // bn_stats blocks (= partial rows)

typedef __attribute__((ext_vector_type(8))) short short8;   // 8 bf16 (4 VGPRs)
typedef __attribute__((ext_vector_type(4))) float f32x4;

__device__ __forceinline__ float bf2f(unsigned short u) {
  union { unsigned int i; float f; } t; t.i = ((unsigned int)u) << 16; return t.f;
}
__device__ __forceinline__ unsigned short f2bf(float f) {
  __hip_bfloat16 h = __float2bfloat16(f);   // RNE hardware convert
  return *reinterpret_cast<unsigned short*>(&h);
}

// ---------------- fused GEMM (+AL epilogue), XCD-chunked ----------------
// A bf16 [M][K]. BtH bf16 [WAVES_GAT*64][K]; BtS bf16 [WAVES_SKIP*64][K].
// Each wave owns 64 cols, B panel register-resident; all waves share tile t.
// blockIdx&7 = XCD -> contiguous tile chunk (A slice ~3.2MB, L2-resident).
// Mapping (m89): A row=lane&15, k=(lane>>4)*8+j; B col=lane&15;
// D col=lane&15, row=(lane>>4)*4+reg.
template<int K, int WAVES_GAT, int WAVES_SKIP>
__global__ __launch_bounds__((WAVES_GAT + WAVES_SKIP) * 64)
void gemm_gat_fused(const unsigned short* __restrict__ A,
                    const unsigned short* __restrict__ BtH,
                    const unsigned short* __restrict__ BtS,
                    const float* __restrict__ a_s, const float* __restrict__ a_d,
                    const float* __restrict__ biasS,
                    unsigned short* __restrict__ Hout,
                    float* __restrict__ als, float* __restrict__ ald,
                    unsigned short* __restrict__ Sout, int M) {
  constexpr int NKS = K / 32;
  constexpr int NH  = WAVES_GAT * 64;
  constexpr int NS  = WAVES_SKIP * 64;
  const int wid  = threadIdx.x >> 6;
  const int lane = threadIdx.x & 63;
  const int r    = lane & 15;
  const int q    = lane >> 4;
  const int koff = q * 8;
  const bool isGat = wid < WAVES_GAT;
  const int colbase = isGat ? wid * 64 : (wid - WAVES_GAT) * 64;
  const unsigned short* Bt = isGat ? BtH : BtS;

  short8 b[4][NKS];
  #pragma unroll
  for (int nf = 0; nf < 4; ++nf)
    #pragma unroll
    for (int ks = 0; ks < NKS; ++ks)
      b[nf][ks] = *(const short8*)(Bt + (size_t)(colbase + nf * 16 + r) * K + ks * 32 + koff);

  float as4[4] = {}, ad4[4] = {};
  if (isGat) {
    #pragma unroll
    for (int nf = 0; nf < 4; ++nf) {
      as4[nf] = a_s[colbase + nf * 16 + r];
      ad4[nf] = a_d[colbase + nf * 16 + r];
    }
  }

  const int ntiles = (M + 15) >> 4;
  const int chunk = (ntiles + 7) >> 3;
  const int xcd   = blockIdx.x & 7;
  const int lo    = xcd * chunk;
  const int hi    = min(lo + chunk, ntiles);
  const int bstep = gridDim.x >> 3;
  for (int t = lo + (blockIdx.x >> 3); t < hi; t += bstep) {
    const int row = t * 16 + r;
    short8 a[NKS];
    #pragma unroll
    for (int ks = 0; ks < NKS; ++ks) {
      a[ks] = (short8)(short)0;
      if (row < M) a[ks] = *(const short8*)(A + (size_t)row * K + ks * 32 + koff);
    }
    f32x4 acc[4];
    #pragma unroll
    for (int nf = 0; nf < 4; ++nf) acc[nf] = (f32x4)0.0f;
    #pragma unroll
    for (int ks = 0; ks < NKS; ++ks)
      #pragma unroll
      for (int nf = 0; nf < 4; ++nf)
        acc[nf] = __builtin_amdgcn_mfma_f32_16x16x32_bf16(a[ks], b[nf][ks], acc[nf], 0, 0, 0);

    const int rbase = t * 16 + q * 4;
    if (isGat) {
      #pragma unroll
      for (int nf = 0; nf < 4; ++nf) {
        const int col = colbase + nf * 16 + r;
        #pragma unroll
        for (int i = 0; i < 4; ++i) {
          const int rr = rbase + i;
          if (rr < M) Hout[(size_t)rr * NH + col] = f2bf(acc[nf][i]);
        }
      }
      #pragma unroll
      for (int i = 0; i < 4; ++i) {
        float s = 0.f, d = 0.f;
        #pragma unroll
        for (int nf = 0; nf < 4; ++nf) {
          s = fmaf(acc[nf][i], as4[nf], s);
          d = fmaf(acc[nf][i], ad4[nf], d);
        }
        #pragma unroll
        for (int m = 8; m >= 1; m >>= 1) {
          s += __shfl_xor(s, m, 64);
          d += __shfl_xor(d, m, 64);
        }
        const int rr = rbase + i;
        if (r == 0 && rr < M) {
          als[(size_t)rr * WAVES_GAT + wid] = s;
          ald[(size_t)rr * WAVES_GAT + wid] = d;
        }
      }
    } else {
      #pragma unroll
      for (int nf = 0; nf < 4; ++nf) {
        const int col = colbase + nf * 16 + r;
        const float bs = biasS[col];
        #pragma unroll
        for (int i = 0; i < 4; ++i) {
          const int rr = rbase + i;
          if (rr < M) Sout[(size_t)rr * NS + col] = f2bf(acc[nf][i] + bs);
        }
      }
    }
  }
}

// ---------------- layer-3 GEMM (64 cols, heads=1) + AL, XCD-chunked --------
__global__ __launch_bounds__(256)
void gemm_gat3(const unsigned short* __restrict__ A, const unsigned short* __restrict__ Bt,
               const float* __restrict__ a_s, const float* __restrict__ a_d,
               unsigned short* __restrict__ Hout, float* __restrict__ als,
               float* __restrict__ ald, int M) {
  constexpr int K = 256, NKS = 8;
  const int wid  = threadIdx.x >> 6;
  const int lane = threadIdx.x & 63;
  const int r    = lane & 15;
  const int q    = lane >> 4;
  const int koff = q * 8;

  short8 b[4][NKS];
  #pragma unroll
  for (int nf = 0; nf < 4; ++nf)
    #pragma unroll
    for (int ks = 0; ks < NKS; ++ks)
      b[nf][ks] = *(const short8*)(Bt + (size_t)(nf * 16 + r) * K + ks * 32 + koff);
  float as4[4], ad4[4];
  #pragma unroll
  for (int nf = 0; nf < 4; ++nf) {
    as4[nf] = a_s[nf * 16 + r];
    ad4[nf] = a_d[nf * 16 + r];
  }

  const int ntiles = (M + 15) >> 4;
  const int chunk = (ntiles + 7) >> 3;
  const int xcd   = blockIdx.x & 7;
  const int lo    = xcd * chunk;
  const int hi    = min(lo + chunk, ntiles);
  const int bstep = (gridDim.x >> 3) * 4;
  for (int t = lo + (blockIdx.x >> 3) * 4 + wid; t < hi; t += bstep) {
    const int row = t * 16 + r;
    short8 a[NKS];
    #pragma unroll
    for (int ks = 0; ks < NKS; ++ks) {
      a[ks] = (short8)(short)0;
      if (row < M) a[ks] = *(const short8*)(A + (size_t)row * K + ks * 32 + koff);
    }
    f32x4 acc[4];
    #pragma unroll
    for (int nf = 0; nf < 4; ++nf) acc[nf] = (f32x4)0.0f;
    #pragma unroll
    for (int ks = 0; ks < NKS; ++ks)
      #pragma unroll
      for (int nf = 0; nf < 4; ++nf)
        acc[nf] = __builtin_amdgcn_mfma_f32_16x16x32_bf16(a[ks], b[nf][ks], acc[nf], 0, 0, 0);

    const int rbase = t * 16 + q * 4;
    #pragma unroll
    for (int nf = 0; nf < 4; ++nf) {
      const int col = nf * 16 + r;
      #pragma unroll
      for (int i = 0; i < 4; ++i) {
        const int rr = rbase + i;
        if (rr < M) Hout[(size_t)rr * 64 + col] = f2bf(acc[nf][i]);
      }
    }
    #pragma unroll
    for (int i = 0; i < 4; ++i) {
      float s = 0.f, d = 0.f;
      #pragma unroll
      for (int nf = 0; nf < 4; ++nf) {
        s = fmaf(acc[nf][i], as4[nf], s);
        d = fmaf(acc[nf][i], ad4[nf], d);
      }
      #pragma unroll
      for (int m = 8; m >= 1; m >>= 1) {
        s += __shfl_xor(s, m, 64);
        d += __shfl_xor(d, m, 64);
      }
      const int rr = rbase + i;
      if (r == 0 && rr < M) { als[rr] = s; ald[rr] = d; }
    }
  }
}

// ---- one-shot prep: x->bf16 + 5 weight transposes + zero cnt ----
__global__ __launch_bounds__(256)
void prep_all(const float* __restrict__ x,
              const float* __restrict__ W1, const float* __restrict__ Ws1,
              const float* __restrict__ W2, const float* __restrict__ Ws2,
              const float* __restrict__ W3,
              unsigned short* __restrict__ xb,
              unsigned short* __restrict__ W1t, unsigned short* __restrict__ Ws1t,
              unsigned short* __restrict__ W2t, unsigned short* __restrict__ Ws2t,
              unsigned short* __restrict__ W3t,
              int* __restrict__ cnt, int n) {
  int idx = blockIdx.x * blockDim.x + threadIdx.x;
  const int nx = n * 32;            // n*128/4 float4 groups
  if (idx < nx) {
    float4 v = ((const float4*)x)[idx];
    ushort4 o;
    o.x = f2bf(v.x); o.y = f2bf(v.y); o.z = f2bf(v.z); o.w = f2bf(v.w);
    ((ushort4*)xb)[idx] = o;
    return;
  }
  idx -= nx;
  if (idx < 256 * 128) { int nn = idx >> 7, kk = idx & 127; W1t[idx]  = f2bf(W1[kk * 256 + nn]);  return; }
  idx -= 256 * 128;
  if (idx < 256 * 128) { int nn = idx >> 7, kk = idx & 127; Ws1t[idx] = f2bf(Ws1[kk * 256 + nn]); return; }
  idx -= 256 * 128;
  if (idx < 256 * 256) { int nn = idx >> 8, kk = idx & 255; W2t[idx]  = f2bf(W2[kk * 256 + nn]);  return; }
  idx -= 256 * 256;
  if (idx < 64 * 256)  { int nn = idx >> 8, kk = idx & 255; Ws2t[idx] = f2bf(Ws2[kk * 64 + nn]);  return; }
  idx -= 64 * 256;
  if (idx < 64 * 256)  { int nn = idx >> 8, kk = idx & 255; W3t[idx]  = f2bf(W3[kk * 64 + nn]); return; }
  idx -= 64 * 256;
  if (idx < n) cnt[idx] = 0;        // count array zero (replaces memset)
}

// ---------------- CSR build (dst-keyed, XCD-chunked by dst range) ----------
__global__ void count_edges(const int* __restrict__ ei, int E, int* __restrict__ counts,
                            int n) {
  const int g = blockIdx.x & 7;
  const int chunk = (n + 7) >> 3;
  const int lo = g * chunk, hi = min(lo + chunk, n);
  const int stride = (gridDim.x >> 3) * blockDim.x;
  for (int i = (blockIdx.x >> 3) * blockDim.x + threadIdx.x; i < E; i += stride) {
    int d = ei[E + i];
    if (d >= lo && d < hi) atomicAdd(&counts[d], 1);
  }
}
__global__ void scan_block(const int* __restrict__ in, int* __restrict__ out,
                           int* __restrict__ bsums, int n) {
  __shared__ int tmp[256];
  int t = threadIdx.x;
  int gid = blockIdx.x * 256 + t;
  int v = (gid < n) ? in[gid] : 0;
  tmp[t] = v;
  __syncthreads();
  #pragma unroll
  for (int off = 1; off < 256; off <<= 1) {
    int x = (t >= off) ? tmp[t - off] : 0;
    __syncthreads();
    tmp[t] += x;
    __syncthreads();
  }
  if (gid < n) out[gid] = tmp[t] - v;
  if (t == 255) bsums[blockIdx.x] = tmp[255];
}
// adds its own serial prefix of bsums (replaces scan_tops) and zeros cnt
__global__ void scan_add(int* __restrict__ rp, const int* __restrict__ bsums,
                         int* __restrict__ cnt, int n, int etot) {
  __shared__ int boff;
  if (threadIdx.x == 0) {
    int s = 0;
    for (int b = 0; b < (int)blockIdx.x; ++b) s += bsums[b];
    boff = s;
  }
  __syncthreads();
  int gid = blockIdx.x * 256 + threadIdx.x;
  if (gid < n) {
    rp[gid] += boff;
    cnt[gid] = 0;
  }
  if (gid == 0) rp[n] = etot;
}
__global__ void fill_edges(const int* __restrict__ ei, int E, const int* __restrict__ rp,
                           int* __restrict__ cursor, int* __restrict__ csr, int n) {
  const int g = blockIdx.x & 7;
  const int chunk = (n + 7) >> 3;
  const int lo = g * chunk, hi = min(lo + chunk, n);
  const int stride = (gridDim.x >> 3) * blockDim.x;
  for (int i = (blockIdx.x >> 3) * blockDim.x + threadIdx.x; i < E; i += stride) {
    int d = ei[E + i];
    if (d >= lo && d < hi) {
      int pos = rp[d] + atomicAdd(&cursor[d], 1);
      csr[pos] = ei[i];
    }
  }
}

// ---------------- wave-per-node segment-softmax aggregation (bf16 H) --------
// One wave per node (full TLP); lane owns CPL contiguous channels; per-lane
// att (independent exp chains). csr indices are wave-uniform -> readfirstlane
// moves them to SGPR (saddr-form gather, less VALU address math). Self-loop
// inline. No segment-max (logits bounded; softmax shift-invariant).
template<int HEADS, int HCt, bool OUT_BF16>
__global__ __launch_bounds__(256)
void gat_aggregate(const unsigned short* __restrict__ H, const float* __restrict__ als,
                   const float* __restrict__ ald, const int* __restrict__ rp,
                   const int* __restrict__ csr, const float* __restrict__ bias,
                   const unsigned short* __restrict__ skip, void* __restrict__ out, int n) {
  constexpr int CPL = HCt / 64;
  int w = (blockIdx.x * blockDim.x + threadIdx.x) >> 6;
  int lane = threadIdx.x & 63;
  if (w >= n) return;
  const int beg = rp[w], end = rp[w + 1];
  const int myhead = (HEADS == 1) ? 0 : (lane >> 4);
  const float adh = ald[(size_t)w * HEADS + myhead];

  auto att = [&](int s) -> float {
    float e = als[(size_t)s * HEADS + myhead] + adh;
    e = fmaxf(e, LRELU_SLOPE * e);
    return __expf(e);
  };

  // self-loop term
  float acc[CPL];
  float ssum = att(w);
  {
    const unsigned short* hp = H + (size_t)w * HCt + lane * CPL;
    if constexpr (CPL == 4) {
      ushort4 hv = *(const ushort4*)hp;
      acc[0] = ssum * bf2f(hv.x); acc[1] = ssum * bf2f(hv.y);
      acc[2] = ssum * bf2f(hv.z); acc[3] = ssum * bf2f(hv.w);
    } else {
      acc[0] = ssum * bf2f(hp[0]);
    }
  }

  int j = beg;
  for (; j + 8 <= end; j += 8) {
    int sidx[8];
    #pragma unroll
    for (int u = 0; u < 8; ++u)
      sidx[u] = __builtin_amdgcn_readfirstlane(csr[j + u]);   // wave-uniform
    if constexpr (CPL == 4) {
      ushort4 hv[8];
      #pragma unroll
      for (int u = 0; u < 8; ++u)
        hv[u] = *(const ushort4*)(H + (size_t)sidx[u] * HCt + lane * 4);
      float ex[8];
      #pragma unroll
      for (int u = 0; u < 8; ++u) ex[u] = att(sidx[u]);
      #pragma unroll
      for (int u = 0; u < 8; ++u) {
        ssum += ex[u];
        acc[0] = fmaf(ex[u], bf2f(hv[u].x), acc[0]);
        acc[1] = fmaf(ex[u], bf2f(hv[u].y), acc[1]);
        acc[2] = fmaf(ex[u], bf2f(hv[u].z), acc[2]);
        acc[3] = fmaf(ex[u], bf2f(hv[u].w), acc[3]);
      }
    } else {
      unsigned short hv[8];
      #pragma unroll
      for (int u = 0; u < 8; ++u) hv[u] = H[(size_t)sidx[u] * HCt + lane];
      float ex[8];
      #pragma unroll
      for (int u = 0; u < 8; ++u) ex[u] = att(sidx[u]);
      #pragma unroll
      for (int u = 0; u < 8; ++u) {
        ssum += ex[u];
        acc[0] = fmaf(ex[u], bf2f(hv[u]), acc[0]);
      }
    }
  }
  for (; j + 4 <= end; j += 4) {
    int sidx[4];
    #pragma unroll
    for (int u = 0; u < 4; ++u)
      sidx[u] = __builtin_amdgcn_readfirstlane(csr[j + u]);
    float ex[4];
    #pragma unroll
    for (int u = 0; u < 4; ++u) ex[u] = att(sidx[u]);
    if constexpr (CPL == 4) {
      ushort4 hv[4];
      #pragma unroll
      for (int u = 0; u < 4; ++u)
        hv[u] = *(const ushort4*)(H + (size_t)sidx[u] * HCt + lane * 4);
      #pragma unroll
      for (int u = 0; u < 4; ++u) {
        ssum += ex[u];
        acc[0] = fmaf(ex[u], bf2f(hv[u].x), acc[0]);
        acc[1] = fmaf(ex[u], bf2f(hv[u].y), acc[1]);
        acc[2] = fmaf(ex[u], bf2f(hv[u].z), acc[2]);
        acc[3] = fmaf(ex[u], bf2f(hv[u].w), acc[3]);
      }
    } else {
      unsigned short hv[4];
      #pragma unroll
      for (int u = 0; u < 4; ++u) hv[u] = H[(size_t)sidx[u] * HCt + lane];
      #pragma unroll
      for (int u = 0; u < 4; ++u) {
        ssum += ex[u];
        acc[0] = fmaf(ex[u], bf2f(hv[u]), acc[0]);
      }
    }
  }
  for (; j < end; ++j) {
    const int s = __builtin_amdgcn_readfirstlane(csr[j]);
    const float ex = att(s);
    ssum += ex;
    const unsigned short* hp = H + (size_t)s * HCt + lane * CPL;
    if constexpr (CPL == 4) {
      ushort4 hv = *(const ushort4*)hp;
      acc[0] = fmaf(ex, bf2f(hv.x), acc[0]);
      acc[1] = fmaf(ex, bf2f(hv.y), acc[1]);
      acc[2] = fmaf(ex, bf2f(hv.z), acc[2]);
      acc[3] = fmaf(ex, bf2f(hv.w), acc[3]);
    } else {
      acc[0] = fmaf(ex, bf2f(hp[0]), acc[0]);
    }
  }

  const float inv = 1.f / (ssum + 1e-16f);
  #pragma unroll
  for (int c = 0; c < CPL; ++c) {
    int ch = lane * CPL + c;
    float v = acc[c] * inv + bias[ch];
    if (skip) v += bf2f(skip[(size_t)w * HCt + ch]);
    if constexpr (OUT_BF16)
      ((unsigned short*)out)[(size_t)w * HCt + ch] = f2bf(v);
    else
      ((float*)out)[(size_t)w * HCt + ch] = v;
  }
}

// ---------------- batch norm stats (vectorized, no global atomics) ----------
__global__ __launch_bounds__(256)
void bn_stats(const unsigned short* __restrict__ X, float* __restrict__ partial, int n) {
  const int lane = threadIdx.x & 63;
  const int rg   = threadIdx.x >> 6;     // 0..3 row groups
  const int c4   = lane * 4;
  float s0 = 0.f, s1 = 0.f, s2 = 0.f, s3 = 0.f;
  float q0 = 0.f, q1 = 0.f, q2 = 0.f, q3 = 0.f;
  const int step = NSTATB * 4;
  int r = blockIdx.x * 4 + rg;
  for (; r + 3 * step < n; r += 4 * step) {
    #pragma unroll
    for (int u = 0; u < 4; ++u) {
      ushort4 v = *(const ushort4*)(X + (size_t)(r + u * step) * 256 + c4);
      float f0 = bf2f(v.x), f1 = bf2f(v.y), f2 = bf2f(v.z), f3 = bf2f(v.w);
      s0 += f0; s1 += f1; s2 += f2; s3 += f3;
      q0 = fmaf(f0, f0, q0); q1 = fmaf(f1, f1, q1);
      q2 = fmaf(f2, f2, q2); q3 = fmaf(f3, f3, q3);
    }
  }
  for (; r < n; r += step) {
    ushort4 v = *(const ushort4*)(X + (size_t)r * 256 + c4);
    float f0 = bf2f(v.x), f1 = bf2f(v.y), f2 = bf2f(v.z), f3 = bf2f(v.w);
    s0 += f0; s1 += f1; s2 += f2; s3 += f3;
    q0 = fmaf(f0, f0, q0); q1 = fmaf(f1, f1, q1);
    q2 = fmaf(f2, f2, q2); q3 = fmaf(f3, f3, q3);
  }
  __shared__ float red[512];
  red[threadIdx.x] = 0.f;
  red[256 + threadIdx.x] = 0.f;
  __syncthreads();
  atomicAdd(&red[c4 + 0], s0); atomicAdd(&red[c4 + 1], s1);
  atomicAdd(&red[c4 + 2], s2); atomicAdd(&red[c4 + 3], s3);
  atomicAdd(&red[256 + c4 + 0], q0); atomicAdd(&red[256 + c4 + 1], q1);
  atomicAdd(&red[256 + c4 + 2], q2); atomicAdd(&red[256 + c4 + 3], q3);
  __syncthreads();
  partial[(size_t)blockIdx.x * 512 + threadIdx.x] = red[threadIdx.x];
  partial[(size_t)blockIdx.x * 512 + 256 + threadIdx.x] = red[256 + threadIdx.x];
}
// reduce NSTATB partial rows; threads 0-255 own sums, 256-511 own sumsqs
__global__ __launch_bounds__(512)
void bn_finalize(const float* __restrict__ partial, const float* __restrict__ gamma,
                 const float* __restrict__ beta, float* __restrict__ scsh, int n) {
  __shared__ float sq[512];
  const int t = threadIdx.x;
  float acc = 0.f;
  #pragma unroll 8
  for (int r = 0; r < NSTATB; ++r) acc += partial[(size_t)r * 512 + t];
  sq[t] = acc;
  __syncthreads();
  if (t < 256) {
    float mean = sq[t] / (float)n;
    float var = sq[256 + t] / (float)n - mean * mean;
    float sc = gamma[t] * rsqrtf(var + 1e-5f);
    scsh[t] = sc;
    scsh[256 + t] = beta[t] - mean * sc;
  }
}
// BN affine + ELU (+bf16 skip) -> bf16; 8 channels per thread (16B loads)
__global__ __launch_bounds__(256)
void bn_apply_elu(const unsigned short* __restrict__ X, const float* __restrict__ scsh,
                  const unsigned short* __restrict__ skip, unsigned short* __restrict__ Y,
                  int total) {
  int i8 = blockIdx.x * blockDim.x + threadIdx.x;
  if (i8 * 8 >= total) return;
  short8 xv = ((const short8*)X)[i8];
  int cb = (i8 * 8) & 255;
  short8 o;
  #pragma unroll
  for (int u = 0; u < 8; ++u) {
    float yv = fmaf(bf2f((unsigned short)xv[u]), scsh[cb + u], scsh[256 + cb + u]);
    yv = (yv > 0.f) ? yv : expm1f(yv);
    if (skip) yv += bf2f(((const unsigned short*)skip)[(size_t)i8 * 8 + u]);
    o[u] = (short)f2bf(yv);
  }
  ((short8*)Y)[i8] = o;
}

// ---------------------------------------------------------------------------
extern "C" void kernel_launch(void* const* d_in, const int* in_sizes, int n_in,
                              void* d_out, int out_size, void* d_ws, size_t ws_size,
                              hipStream_t stream) {
  const float* x   = (const float*)d_in[0];
  const int*   ei  = (const int*)d_in[1];
  const float* W1  = (const float*)d_in[2];
  const float* as1 = (const float*)d_in[3];
  const float* ad1 = (const float*)d_in[4];
  const float* b1  = (const float*)d_in[5];
  const float* g1  = (const float*)d_in[6];
  const float* bb1 = (const float*)d_in[7];
  const float* W2  = (const float*)d_in[8];
  const float* as2 = (const float*)d_in[9];
  const float* ad2 = (const float*)d_in[10];
  const float* b2  = (const float*)d_in[11];
  const float* g2  = (const float*)d_in[12];
  const float* bb2 = (const float*)d_in[13];
  const float* W3  = (const float*)d_in[14];
  const float* as3 = (const float*)d_in[15];
  const float* ad3 = (const float*)d_in[16];
  const float* b3  = (const float*)d_in[17];
  const float* Ws1 = (const float*)d_in[18];
  const float* bs1 = (const float*)d_in[19];
  const float* Ws2 = (const float*)d_in[20];
  const float* bs2 = (const float*)d_in[21];

  const int n = in_sizes[0] / 128;   // 50000
  const int E = in_sizes[1] / 2;     // 800000

  char* wsp = (char*)d_ws;
  auto carve = [&](size_t bytes) -> void* {
    void* p = (void*)wsp;
    wsp += (bytes + 255) & ~(size_t)255;
    return p;
  };
  unsigned short* Hb  = (unsigned short*)carve((size_t)n * 256 * 2);  // GEMM out (node-major)
  unsigned short* hb  = (unsigned short*)carve((size_t)n * 256 * 2);  // BN/ELU out
  unsigned short* xbD = (unsigned short*)carve((size_t)n * 128 * 2);  // xb, then D
  unsigned short* xb  = xbD;
  unsigned short* D   = xbD;            // x_skip (bf16, n*64); written after xb dead
  unsigned short* Bv  = (unsigned short*)carve((size_t)n * 256 * 2);  // x_init
  unsigned short* Cv  = (unsigned short*)carve((size_t)n * 256 * 2);  // aggregate out
  float* als  = (float*)carve((size_t)n * 4 * 4);
  float* ald  = (float*)carve((size_t)n * 4 * 4);
  int*   rp   = (int*)carve((size_t)(n + 1) * 4);
  int*   cnt  = (int*)carve((size_t)n * 4);
  int*   bsums= (int*)carve(256 * 4);
  int*   csr  = (int*)carve((size_t)E * 4);
  float* partial = (float*)carve((size_t)NSTATB * 512 * 4);  // BN partials
  float* scsh = (float*)carve(512 * 4);
  unsigned short* W1t  = (unsigned short*)carve(128 * 256 * 2);
  unsigned short* Ws1t = (unsigned short*)carve(128 * 256 * 2);
  unsigned short* W2t  = (unsigned short*)carve(256 * 256 * 2);
  unsigned short* Ws2t = (unsigned short*)carve(256 * 64 * 2);
  unsigned short* W3t  = (unsigned short*)carve(256 * 64 * 2);

  const int NB = (n + 255) / 256;

  // ---- prep first: conversions + cnt zero (no memsets) ----
  {
    const int total = n * 32 + 2 * 256 * 128 + 256 * 256 + 2 * 64 * 256 + n;
    prep_all<<<(total + 255) / 256, 256, 0, stream>>>(x, W1, Ws1, W2, Ws2, W3,
                                                      xb, W1t, Ws1t, W2t, Ws2t, W3t,
                                                      cnt, n);
  }

  // ---- CSR build (real edges only; XCD-chunked by dst range) ----
  count_edges<<<2048, 256, 0, stream>>>(ei, E, cnt, n);
  scan_block<<<NB, 256, 0, stream>>>(cnt, rp, bsums, n);
  scan_add<<<NB, 256, 0, stream>>>(rp, bsums, cnt, n, E);   // + tops + cursor zero
  fill_edges<<<2048, 256, 0, stream>>>(ei, E, rp, cnt, csr, n);

  const int wgrid = (n * 64 + 255) / 256;   // one wave per node
  const int e8grid = (n * 256 / 8 + 255) / 256;

  // ---- layer 1: x[128] -> GAT(4x64)+AL + x_init, fused ----
  gemm_gat_fused<128, 4, 4><<<1024, 512, 0, stream>>>(
      xb, W1t, Ws1t, as1, ad1, bs1, Hb, als, ald, Bv, n);
  gat_aggregate<4, 256, true><<<wgrid, 256, 0, stream>>>(Hb, als, ald, rp, csr, b1,
                                                         nullptr, Cv, n);
  bn_stats<<<NSTATB, 256, 0, stream>>>(Cv, partial, n);
  bn_finalize<<<1, 512, 0, stream>>>(partial, g1, bb1, scsh, n);
  bn_apply_elu<<<e8grid, 256, 0, stream>>>(Cv, scsh, Bv, hb, n * 256);   // h1 -> hb

  // ---- layer 2: h1 -> GAT(4x64)+AL + x_skip, fused ----
  gemm_gat_fused<256, 4, 1><<<1024, 320, 0, stream>>>(
      hb, W2t, Ws2t, as2, ad2, bs2, Hb, als, ald, D, n);
  gat_aggregate<4, 256, true><<<wgrid, 256, 0, stream>>>(Hb, als, ald, rp, csr, b2,
                                                         nullptr, Cv, n);
  bn_stats<<<NSTATB, 256, 0, stream>>>(Cv, partial, n);
  bn_finalize<<<1, 512, 0, stream>>>(partial, g2, bb2, scsh, n);
  bn_apply_elu<<<e8grid, 256, 0, stream>>>(Cv, scsh, nullptr, hb, n * 256); // h2 -> hb

  // ---- layer 3: heads=1, mean(=identity), + b3 + x_skip -> d_out ----
  gemm_gat3<<<1024, 256, 0, stream>>>(hb, W3t, as3, ad3, Hb, als, ald, n);
  gat_aggregate<1, 64, false><<<wgrid, 256, 0, stream>>>(Hb, als, ald, rp, csr, b3, D,
                                                         d_out, n);
}

// Round 16
// 442.298 us; speedup vs baseline: 1.2563x; 1.2563x over previous
//
#include <hip/hip_runtime.h>
#include <hip/hip_bf16.h>
#include <cstdint>
#include <cstddef>

// ---------------------------------------------------------------------------
// GATWithSkip: 3x GATConv + BN/ELU/skips on MI355X.
// R14 (442us, BEST): vectorized bn_stats; R10 aggregate/GEMM/CSR; diet.
// R15 (556us) bundled 4 tail changes, all reverted: GEMM grid 1024 (halved
//   B-panel amortization), scan_tops fold (serial straggler), ushort8
//   bn_apply (scalar skip loads), readfirstlane (neutral).
// R16: exact R14 restore.
// ---------------------------------------------------------------------------

#define LRELU_SLOPE 0.2f
#define NSTATB 256   // bn_stats blocks (= partial rows)

typedef __attribute__((ext_vector_type(8))) short short8;   // 8 bf16 (4 VGPRs)
typedef __attribute__((ext_vector_type(4))) float f32x4;

__device__ __forceinline__ float bf2f(unsigned short u) {
  union { unsigned int i; float f; } t; t.i = ((unsigned int)u) << 16; return t.f;
}
__device__ __forceinline__ unsigned short f2bf(float f) {
  __hip_bfloat16 h = __float2bfloat16(f);   // RNE hardware convert
  return *reinterpret_cast<unsigned short*>(&h);
}

// ---------------- fused GEMM (+AL epilogue), XCD-chunked ----------------
// A bf16 [M][K]. BtH bf16 [WAVES_GAT*64][K]; BtS bf16 [WAVES_SKIP*64][K].
// Each wave owns 64 cols, B panel register-resident; all waves share tile t.
// blockIdx&7 = XCD -> contiguous tile chunk (A slice ~3.2MB, L2-resident).
// Mapping (m89): A row=lane&15, k=(lane>>4)*8+j; B col=lane&15;
// D col=lane&15, row=(lane>>4)*4+reg.
template<int K, int WAVES_GAT, int WAVES_SKIP>
__global__ __launch_bounds__((WAVES_GAT + WAVES_SKIP) * 64)
void gemm_gat_fused(const unsigned short* __restrict__ A,
                    const unsigned short* __restrict__ BtH,
                    const unsigned short* __restrict__ BtS,
                    const float* __restrict__ a_s, const float* __restrict__ a_d,
                    const float* __restrict__ biasS,
                    unsigned short* __restrict__ Hout,
                    float* __restrict__ als, float* __restrict__ ald,
                    unsigned short* __restrict__ Sout, int M) {
  constexpr int NKS = K / 32;
  constexpr int NH  = WAVES_GAT * 64;
  constexpr int NS  = WAVES_SKIP * 64;
  const int wid  = threadIdx.x >> 6;
  const int lane = threadIdx.x & 63;
  const int r    = lane & 15;
  const int q    = lane >> 4;
  const int koff = q * 8;
  const bool isGat = wid < WAVES_GAT;
  const int colbase = isGat ? wid * 64 : (wid - WAVES_GAT) * 64;
  const unsigned short* Bt = isGat ? BtH : BtS;

  short8 b[4][NKS];
  #pragma unroll
  for (int nf = 0; nf < 4; ++nf)
    #pragma unroll
    for (int ks = 0; ks < NKS; ++ks)
      b[nf][ks] = *(const short8*)(Bt + (size_t)(colbase + nf * 16 + r) * K + ks * 32 + koff);

  float as4[4] = {}, ad4[4] = {};
  if (isGat) {
    #pragma unroll
    for (int nf = 0; nf < 4; ++nf) {
      as4[nf] = a_s[colbase + nf * 16 + r];
      ad4[nf] = a_d[colbase + nf * 16 + r];
    }
  }

  const int ntiles = (M + 15) >> 4;
  const int chunk = (ntiles + 7) >> 3;
  const int xcd   = blockIdx.x & 7;
  const int lo    = xcd * chunk;
  const int hi    = min(lo + chunk, ntiles);
  const int bstep = gridDim.x >> 3;
  for (int t = lo + (blockIdx.x >> 3); t < hi; t += bstep) {
    const int row = t * 16 + r;
    short8 a[NKS];
    #pragma unroll
    for (int ks = 0; ks < NKS; ++ks) {
      a[ks] = (short8)(short)0;
      if (row < M) a[ks] = *(const short8*)(A + (size_t)row * K + ks * 32 + koff);
    }
    f32x4 acc[4];
    #pragma unroll
    for (int nf = 0; nf < 4; ++nf) acc[nf] = (f32x4)0.0f;
    #pragma unroll
    for (int ks = 0; ks < NKS; ++ks)
      #pragma unroll
      for (int nf = 0; nf < 4; ++nf)
        acc[nf] = __builtin_amdgcn_mfma_f32_16x16x32_bf16(a[ks], b[nf][ks], acc[nf], 0, 0, 0);

    const int rbase = t * 16 + q * 4;
    if (isGat) {
      #pragma unroll
      for (int nf = 0; nf < 4; ++nf) {
        const int col = colbase + nf * 16 + r;
        #pragma unroll
        for (int i = 0; i < 4; ++i) {
          const int rr = rbase + i;
          if (rr < M) Hout[(size_t)rr * NH + col] = f2bf(acc[nf][i]);
        }
      }
      #pragma unroll
      for (int i = 0; i < 4; ++i) {
        float s = 0.f, d = 0.f;
        #pragma unroll
        for (int nf = 0; nf < 4; ++nf) {
          s = fmaf(acc[nf][i], as4[nf], s);
          d = fmaf(acc[nf][i], ad4[nf], d);
        }
        #pragma unroll
        for (int m = 8; m >= 1; m >>= 1) {
          s += __shfl_xor(s, m, 64);
          d += __shfl_xor(d, m, 64);
        }
        const int rr = rbase + i;
        if (r == 0 && rr < M) {
          als[(size_t)rr * WAVES_GAT + wid] = s;
          ald[(size_t)rr * WAVES_GAT + wid] = d;
        }
      }
    } else {
      #pragma unroll
      for (int nf = 0; nf < 4; ++nf) {
        const int col = colbase + nf * 16 + r;
        const float bs = biasS[col];
        #pragma unroll
        for (int i = 0; i < 4; ++i) {
          const int rr = rbase + i;
          if (rr < M) Sout[(size_t)rr * NS + col] = f2bf(acc[nf][i] + bs);
        }
      }
    }
  }
}

// ---------------- layer-3 GEMM (64 cols, heads=1) + AL, XCD-chunked --------
__global__ __launch_bounds__(256)
void gemm_gat3(const unsigned short* __restrict__ A, const unsigned short* __restrict__ Bt,
               const float* __restrict__ a_s, const float* __restrict__ a_d,
               unsigned short* __restrict__ Hout, float* __restrict__ als,
               float* __restrict__ ald, int M) {
  constexpr int K = 256, NKS = 8;
  const int wid  = threadIdx.x >> 6;
  const int lane = threadIdx.x & 63;
  const int r    = lane & 15;
  const int q    = lane >> 4;
  const int koff = q * 8;

  short8 b[4][NKS];
  #pragma unroll
  for (int nf = 0; nf < 4; ++nf)
    #pragma unroll
    for (int ks = 0; ks < NKS; ++ks)
      b[nf][ks] = *(const short8*)(Bt + (size_t)(nf * 16 + r) * K + ks * 32 + koff);
  float as4[4], ad4[4];
  #pragma unroll
  for (int nf = 0; nf < 4; ++nf) {
    as4[nf] = a_s[nf * 16 + r];
    ad4[nf] = a_d[nf * 16 + r];
  }

  const int ntiles = (M + 15) >> 4;
  const int chunk = (ntiles + 7) >> 3;
  const int xcd   = blockIdx.x & 7;
  const int lo    = xcd * chunk;
  const int hi    = min(lo + chunk, ntiles);
  const int bstep = (gridDim.x >> 3) * 4;
  for (int t = lo + (blockIdx.x >> 3) * 4 + wid; t < hi; t += bstep) {
    const int row = t * 16 + r;
    short8 a[NKS];
    #pragma unroll
    for (int ks = 0; ks < NKS; ++ks) {
      a[ks] = (short8)(short)0;
      if (row < M) a[ks] = *(const short8*)(A + (size_t)row * K + ks * 32 + koff);
    }
    f32x4 acc[4];
    #pragma unroll
    for (int nf = 0; nf < 4; ++nf) acc[nf] = (f32x4)0.0f;
    #pragma unroll
    for (int ks = 0; ks < NKS; ++ks)
      #pragma unroll
      for (int nf = 0; nf < 4; ++nf)
        acc[nf] = __builtin_amdgcn_mfma_f32_16x16x32_bf16(a[ks], b[nf][ks], acc[nf], 0, 0, 0);

    const int rbase = t * 16 + q * 4;
    #pragma unroll
    for (int nf = 0; nf < 4; ++nf) {
      const int col = nf * 16 + r;
      #pragma unroll
      for (int i = 0; i < 4; ++i) {
        const int rr = rbase + i;
        if (rr < M) Hout[(size_t)rr * 64 + col] = f2bf(acc[nf][i]);
      }
    }
    #pragma unroll
    for (int i = 0; i < 4; ++i) {
      float s = 0.f, d = 0.f;
      #pragma unroll
      for (int nf = 0; nf < 4; ++nf) {
        s = fmaf(acc[nf][i], as4[nf], s);
        d = fmaf(acc[nf][i], ad4[nf], d);
      }
      #pragma unroll
      for (int m = 8; m >= 1; m >>= 1) {
        s += __shfl_xor(s, m, 64);
        d += __shfl_xor(d, m, 64);
      }
      const int rr = rbase + i;
      if (r == 0 && rr < M) { als[rr] = s; ald[rr] = d; }
    }
  }
}

// ---- one-shot prep: x->bf16 + 5 weight transposes + zero cnt ----
__global__ __launch_bounds__(256)
void prep_all(const float* __restrict__ x,
              const float* __restrict__ W1, const float* __restrict__ Ws1,
              const float* __restrict__ W2, const float* __restrict__ Ws2,
              const float* __restrict__ W3,
              unsigned short* __restrict__ xb,
              unsigned short* __restrict__ W1t, unsigned short* __restrict__ Ws1t,
              unsigned short* __restrict__ W2t, unsigned short* __restrict__ Ws2t,
              unsigned short* __restrict__ W3t,
              int* __restrict__ cnt, int n) {
  int idx = blockIdx.x * blockDim.x + threadIdx.x;
  const int nx = n * 32;            // n*128/4 float4 groups
  if (idx < nx) {
    float4 v = ((const float4*)x)[idx];
    ushort4 o;
    o.x = f2bf(v.x); o.y = f2bf(v.y); o.z = f2bf(v.z); o.w = f2bf(v.w);
    ((ushort4*)xb)[idx] = o;
    return;
  }
  idx -= nx;
  if (idx < 256 * 128) { int nn = idx >> 7, kk = idx & 127; W1t[idx]  = f2bf(W1[kk * 256 + nn]);  return; }
  idx -= 256 * 128;
  if (idx < 256 * 128) { int nn = idx >> 7, kk = idx & 127; Ws1t[idx] = f2bf(Ws1[kk * 256 + nn]); return; }
  idx -= 256 * 128;
  if (idx < 256 * 256) { int nn = idx >> 8, kk = idx & 255; W2t[idx]  = f2bf(W2[kk * 256 + nn]);  return; }
  idx -= 256 * 256;
  if (idx < 64 * 256)  { int nn = idx >> 8, kk = idx & 255; Ws2t[idx] = f2bf(Ws2[kk * 64 + nn]);  return; }
  idx -= 64 * 256;
  if (idx < 64 * 256)  { int nn = idx >> 8, kk = idx & 255; W3t[idx]  = f2bf(W3[kk * 64 + nn]); return; }
  idx -= 64 * 256;
  if (idx < n) cnt[idx] = 0;        // count array zero (replaces memset)
}

// ---------------- CSR build (dst-keyed, XCD-chunked by dst range) ----------
__global__ void count_edges(const int* __restrict__ ei, int E, int* __restrict__ counts,
                            int n) {
  const int g = blockIdx.x & 7;
  const int chunk = (n + 7) >> 3;
  const int lo = g * chunk, hi = min(lo + chunk, n);
  const int stride = (gridDim.x >> 3) * blockDim.x;
  for (int i = (blockIdx.x >> 3) * blockDim.x + threadIdx.x; i < E; i += stride) {
    int d = ei[E + i];
    if (d >= lo && d < hi) atomicAdd(&counts[d], 1);
  }
}
__global__ void scan_block(const int* __restrict__ in, int* __restrict__ out,
                           int* __restrict__ bsums, int n) {
  __shared__ int tmp[256];
  int t = threadIdx.x;
  int gid = blockIdx.x * 256 + t;
  int v = (gid < n) ? in[gid] : 0;
  tmp[t] = v;
  __syncthreads();
  #pragma unroll
  for (int off = 1; off < 256; off <<= 1) {
    int x = (t >= off) ? tmp[t - off] : 0;
    __syncthreads();
    tmp[t] += x;
    __syncthreads();
  }
  if (gid < n) out[gid] = tmp[t] - v;
  if (t == 255) bsums[blockIdx.x] = tmp[255];
}
__global__ void scan_tops(const int* __restrict__ bsums, int* __restrict__ boffs, int nb) {
  __shared__ int tmp[256];
  int t = threadIdx.x;
  int v = (t < nb) ? bsums[t] : 0;
  tmp[t] = v;
  __syncthreads();
  #pragma unroll
  for (int off = 1; off < 256; off <<= 1) {
    int x = (t >= off) ? tmp[t - off] : 0;
    __syncthreads();
    tmp[t] += x;
    __syncthreads();
  }
  if (t < nb) boffs[t] = tmp[t] - v;
}
// also zeros cnt (cursor for fill_edges) — removes a memset dispatch
__global__ void scan_add(int* __restrict__ rp, const int* __restrict__ boffs,
                         int* __restrict__ cnt, int n, int etot) {
  int gid = blockIdx.x * 256 + threadIdx.x;
  if (gid < n) {
    rp[gid] += boffs[blockIdx.x];
    cnt[gid] = 0;
  }
  if (gid == 0) rp[n] = etot;
}
__global__ void fill_edges(const int* __restrict__ ei, int E, const int* __restrict__ rp,
                           int* __restrict__ cursor, int* __restrict__ csr, int n) {
  const int g = blockIdx.x & 7;
  const int chunk = (n + 7) >> 3;
  const int lo = g * chunk, hi = min(lo + chunk, n);
  const int stride = (gridDim.x >> 3) * blockDim.x;
  for (int i = (blockIdx.x >> 3) * blockDim.x + threadIdx.x; i < E; i += stride) {
    int d = ei[E + i];
    if (d >= lo && d < hi) {
      int pos = rp[d] + atomicAdd(&cursor[d], 1);
      csr[pos] = ei[i];
    }
  }
}

// ---------------- wave-per-node segment-softmax aggregation (bf16 H) --------
// One wave per node (full TLP); lane owns CPL contiguous channels; per-lane
// att (independent exp chains). Self-loop inline. No segment-max (logits
// bounded; softmax shift-invariant). R10-proven body, untouched.
template<int HEADS, int HCt, bool OUT_BF16>
__global__ __launch_bounds__(256)
void gat_aggregate(const unsigned short* __restrict__ H, const float* __restrict__ als,
                   const float* __restrict__ ald, const int* __restrict__ rp,
                   const int* __restrict__ csr, const float* __restrict__ bias,
                   const unsigned short* __restrict__ skip, void* __restrict__ out, int n) {
  constexpr int CPL = HCt / 64;
  int w = (blockIdx.x * blockDim.x + threadIdx.x) >> 6;
  int lane = threadIdx.x & 63;
  if (w >= n) return;
  const int beg = rp[w], end = rp[w + 1];
  const int myhead = (HEADS == 1) ? 0 : (lane >> 4);
  const float adh = ald[(size_t)w * HEADS + myhead];

  auto att = [&](int s) -> float {
    float e = als[(size_t)s * HEADS + myhead] + adh;
    e = fmaxf(e, LRELU_SLOPE * e);
    return __expf(e);
  };

  // self-loop term
  float acc[CPL];
  float ssum = att(w);
  {
    const unsigned short* hp = H + (size_t)w * HCt + lane * CPL;
    if constexpr (CPL == 4) {
      ushort4 hv = *(const ushort4*)hp;
      acc[0] = ssum * bf2f(hv.x); acc[1] = ssum * bf2f(hv.y);
      acc[2] = ssum * bf2f(hv.z); acc[3] = ssum * bf2f(hv.w);
    } else {
      acc[0] = ssum * bf2f(hp[0]);
    }
  }

  int j = beg;
  for (; j + 8 <= end; j += 8) {
    int sidx[8];
    #pragma unroll
    for (int u = 0; u < 8; ++u) sidx[u] = csr[j + u];
    if constexpr (CPL == 4) {
      ushort4 hv[8];
      #pragma unroll
      for (int u = 0; u < 8; ++u)
        hv[u] = *(const ushort4*)(H + (size_t)sidx[u] * HCt + lane * 4);
      float ex[8];
      #pragma unroll
      for (int u = 0; u < 8; ++u) ex[u] = att(sidx[u]);
      #pragma unroll
      for (int u = 0; u < 8; ++u) {
        ssum += ex[u];
        acc[0] = fmaf(ex[u], bf2f(hv[u].x), acc[0]);
        acc[1] = fmaf(ex[u], bf2f(hv[u].y), acc[1]);
        acc[2] = fmaf(ex[u], bf2f(hv[u].z), acc[2]);
        acc[3] = fmaf(ex[u], bf2f(hv[u].w), acc[3]);
      }
    } else {
      unsigned short hv[8];
      #pragma unroll
      for (int u = 0; u < 8; ++u) hv[u] = H[(size_t)sidx[u] * HCt + lane];
      float ex[8];
      #pragma unroll
      for (int u = 0; u < 8; ++u) ex[u] = att(sidx[u]);
      #pragma unroll
      for (int u = 0; u < 8; ++u) {
        ssum += ex[u];
        acc[0] = fmaf(ex[u], bf2f(hv[u]), acc[0]);
      }
    }
  }
  for (; j + 4 <= end; j += 4) {
    int sidx[4];
    #pragma unroll
    for (int u = 0; u < 4; ++u) sidx[u] = csr[j + u];
    float ex[4];
    #pragma unroll
    for (int u = 0; u < 4; ++u) ex[u] = att(sidx[u]);
    if constexpr (CPL == 4) {
      ushort4 hv[4];
      #pragma unroll
      for (int u = 0; u < 4; ++u)
        hv[u] = *(const ushort4*)(H + (size_t)sidx[u] * HCt + lane * 4);
      #pragma unroll
      for (int u = 0; u < 4; ++u) {
        ssum += ex[u];
        acc[0] = fmaf(ex[u], bf2f(hv[u].x), acc[0]);
        acc[1] = fmaf(ex[u], bf2f(hv[u].y), acc[1]);
        acc[2] = fmaf(ex[u], bf2f(hv[u].z), acc[2]);
        acc[3] = fmaf(ex[u], bf2f(hv[u].w), acc[3]);
      }
    } else {
      unsigned short hv[4];
      #pragma unroll
      for (int u = 0; u < 4; ++u) hv[u] = H[(size_t)sidx[u] * HCt + lane];
      #pragma unroll
      for (int u = 0; u < 4; ++u) {
        ssum += ex[u];
        acc[0] = fmaf(ex[u], bf2f(hv[u]), acc[0]);
      }
    }
  }
  for (; j < end; ++j) {
    const int s = csr[j];
    const float ex = att(s);
    ssum += ex;
    const unsigned short* hp = H + (size_t)s * HCt + lane * CPL;
    if constexpr (CPL == 4) {
      ushort4 hv = *(const ushort4*)hp;
      acc[0] = fmaf(ex, bf2f(hv.x), acc[0]);
      acc[1] = fmaf(ex, bf2f(hv.y), acc[1]);
      acc[2] = fmaf(ex, bf2f(hv.z), acc[2]);
      acc[3] = fmaf(ex, bf2f(hv.w), acc[3]);
    } else {
      acc[0] = fmaf(ex, bf2f(hp[0]), acc[0]);
    }
  }

  const float inv = 1.f / (ssum + 1e-16f);
  #pragma unroll
  for (int c = 0; c < CPL; ++c) {
    int ch = lane * CPL + c;
    float v = acc[c] * inv + bias[ch];
    if (skip) v += bf2f(skip[(size_t)w * HCt + ch]);
    if constexpr (OUT_BF16)
      ((unsigned short*)out)[(size_t)w * HCt + ch] = f2bf(v);
    else
      ((float*)out)[(size_t)w * HCt + ch] = v;
  }
}

// ---------------- batch norm stats (vectorized, no global atomics) ----------
// Lane owns channel-quad (lane*4); a wave reads one full 512B row (coalesced
// ushort4). Rows x4 unrolled -> 4 independent loads in flight. Per-block LDS
// reduce, then write partial[block][512] (no atomics).
__global__ __launch_bounds__(256)
void bn_stats(const unsigned short* __restrict__ X, float* __restrict__ partial, int n) {
  const int lane = threadIdx.x & 63;
  const int rg   = threadIdx.x >> 6;     // 0..3 row groups
  const int c4   = lane * 4;
  float s0 = 0.f, s1 = 0.f, s2 = 0.f, s3 = 0.f;
  float q0 = 0.f, q1 = 0.f, q2 = 0.f, q3 = 0.f;
  const int step = NSTATB * 4;
  int r = blockIdx.x * 4 + rg;
  for (; r + 3 * step < n; r += 4 * step) {
    #pragma unroll
    for (int u = 0; u < 4; ++u) {
      ushort4 v = *(const ushort4*)(X + (size_t)(r + u * step) * 256 + c4);
      float f0 = bf2f(v.x), f1 = bf2f(v.y), f2 = bf2f(v.z), f3 = bf2f(v.w);
      s0 += f0; s1 += f1; s2 += f2; s3 += f3;
      q0 = fmaf(f0, f0, q0); q1 = fmaf(f1, f1, q1);
      q2 = fmaf(f2, f2, q2); q3 = fmaf(f3, f3, q3);
    }
  }
  for (; r < n; r += step) {
    ushort4 v = *(const ushort4*)(X + (size_t)r * 256 + c4);
    float f0 = bf2f(v.x), f1 = bf2f(v.y), f2 = bf2f(v.z), f3 = bf2f(v.w);
    s0 += f0; s1 += f1; s2 += f2; s3 += f3;
    q0 = fmaf(f0, f0, q0); q1 = fmaf(f1, f1, q1);
    q2 = fmaf(f2, f2, q2); q3 = fmaf(f3, f3, q3);
  }
  __shared__ float red[512];
  red[threadIdx.x] = 0.f;
  red[256 + threadIdx.x] = 0.f;
  __syncthreads();
  atomicAdd(&red[c4 + 0], s0); atomicAdd(&red[c4 + 1], s1);
  atomicAdd(&red[c4 + 2], s2); atomicAdd(&red[c4 + 3], s3);
  atomicAdd(&red[256 + c4 + 0], q0); atomicAdd(&red[256 + c4 + 1], q1);
  atomicAdd(&red[256 + c4 + 2], q2); atomicAdd(&red[256 + c4 + 3], q3);
  __syncthreads();
  partial[(size_t)blockIdx.x * 512 + threadIdx.x] = red[threadIdx.x];
  partial[(size_t)blockIdx.x * 512 + 256 + threadIdx.x] = red[256 + threadIdx.x];
}
// reduce NSTATB partial rows; threads 0-255 own sums, 256-511 own sumsqs
__global__ __launch_bounds__(512)
void bn_finalize(const float* __restrict__ partial, const float* __restrict__ gamma,
                 const float* __restrict__ beta, float* __restrict__ scsh, int n) {
  __shared__ float sq[512];
  const int t = threadIdx.x;
  float acc = 0.f;
  #pragma unroll 8
  for (int r = 0; r < NSTATB; ++r) acc += partial[(size_t)r * 512 + t];
  sq[t] = acc;
  __syncthreads();
  if (t < 256) {
    float mean = sq[t] / (float)n;
    float var = sq[256 + t] / (float)n - mean * mean;
    float sc = gamma[t] * rsqrtf(var + 1e-5f);
    scsh[t] = sc;
    scsh[256 + t] = beta[t] - mean * sc;
  }
}
// BN affine + ELU (+bf16 skip) -> bf16 (all node-major)
__global__ __launch_bounds__(256)
void bn_apply_elu(const unsigned short* __restrict__ X, const float* __restrict__ scsh,
                  const unsigned short* __restrict__ skip, unsigned short* __restrict__ Y,
                  int total) {
  int i4 = blockIdx.x * blockDim.x + threadIdx.x;
  if (i4 * 4 >= total) return;
  ushort4 xv = ((const ushort4*)X)[i4];
  int cb = (i4 * 4) & 255;
  float4 sc = *(const float4*)(scsh + cb);
  float4 sh = *(const float4*)(scsh + 256 + cb);
  float4 y;
  y.x = fmaf(bf2f(xv.x), sc.x, sh.x);
  y.y = fmaf(bf2f(xv.y), sc.y, sh.y);
  y.z = fmaf(bf2f(xv.z), sc.z, sh.z);
  y.w = fmaf(bf2f(xv.w), sc.w, sh.w);
  y.x = (y.x > 0.f) ? y.x : expm1f(y.x);
  y.y = (y.y > 0.f) ? y.y : expm1f(y.y);
  y.z = (y.z > 0.f) ? y.z : expm1f(y.z);
  y.w = (y.w > 0.f) ? y.w : expm1f(y.w);
  if (skip) {
    ushort4 s4 = ((const ushort4*)skip)[i4];
    y.x += bf2f(s4.x); y.y += bf2f(s4.y); y.z += bf2f(s4.z); y.w += bf2f(s4.w);
  }
  ushort4 o;
  o.x = f2bf(y.x); o.y = f2bf(y.y); o.z = f2bf(y.z); o.w = f2bf(y.w);
  ((ushort4*)Y)[i4] = o;
}

// ---------------------------------------------------------------------------
extern "C" void kernel_launch(void* const* d_in, const int* in_sizes, int n_in,
                              void* d_out, int out_size, void* d_ws, size_t ws_size,
                              hipStream_t stream) {
  const float* x   = (const float*)d_in[0];
  const int*   ei  = (const int*)d_in[1];
  const float* W1  = (const float*)d_in[2];
  const float* as1 = (const float*)d_in[3];
  const float* ad1 = (const float*)d_in[4];
  const float* b1  = (const float*)d_in[5];
  const float* g1  = (const float*)d_in[6];
  const float* bb1 = (const float*)d_in[7];
  const float* W2  = (const float*)d_in[8];
  const float* as2 = (const float*)d_in[9];
  const float* ad2 = (const float*)d_in[10];
  const float* b2  = (const float*)d_in[11];
  const float* g2  = (const float*)d_in[12];
  const float* bb2 = (const float*)d_in[13];
  const float* W3  = (const float*)d_in[14];
  const float* as3 = (const float*)d_in[15];
  const float* ad3 = (const float*)d_in[16];
  const float* b3  = (const float*)d_in[17];
  const float* Ws1 = (const float*)d_in[18];
  const float* bs1 = (const float*)d_in[19];
  const float* Ws2 = (const float*)d_in[20];
  const float* bs2 = (const float*)d_in[21];

  const int n = in_sizes[0] / 128;   // 50000
  const int E = in_sizes[1] / 2;     // 800000

  char* wsp = (char*)d_ws;
  auto carve = [&](size_t bytes) -> void* {
    void* p = (void*)wsp;
    wsp += (bytes + 255) & ~(size_t)255;
    return p;
  };
  unsigned short* Hb  = (unsigned short*)carve((size_t)n * 256 * 2);  // GEMM out (node-major)
  unsigned short* hb  = (unsigned short*)carve((size_t)n * 256 * 2);  // BN/ELU out
  unsigned short* xbD = (unsigned short*)carve((size_t)n * 128 * 2);  // xb, then D
  unsigned short* xb  = xbD;
  unsigned short* D   = xbD;            // x_skip (bf16, n*64); written after xb dead
  unsigned short* Bv  = (unsigned short*)carve((size_t)n * 256 * 2);  // x_init
  unsigned short* Cv  = (unsigned short*)carve((size_t)n * 256 * 2);  // aggregate out
  float* als  = (float*)carve((size_t)n * 4 * 4);
  float* ald  = (float*)carve((size_t)n * 4 * 4);
  int*   rp   = (int*)carve((size_t)(n + 1) * 4);
  int*   cnt  = (int*)carve((size_t)n * 4);
  int*   bsums= (int*)carve(256 * 4);
  int*   boffs= (int*)carve(256 * 4);
  int*   csr  = (int*)carve((size_t)E * 4);
  float* partial = (float*)carve((size_t)NSTATB * 512 * 4);  // BN partials
  float* scsh = (float*)carve(512 * 4);
  unsigned short* W1t  = (unsigned short*)carve(128 * 256 * 2);
  unsigned short* Ws1t = (unsigned short*)carve(128 * 256 * 2);
  unsigned short* W2t  = (unsigned short*)carve(256 * 256 * 2);
  unsigned short* Ws2t = (unsigned short*)carve(256 * 64 * 2);
  unsigned short* W3t  = (unsigned short*)carve(256 * 64 * 2);

  const int NB = (n + 255) / 256;

  // ---- prep first: conversions + cnt zero (no memsets) ----
  {
    const int total = n * 32 + 2 * 256 * 128 + 256 * 256 + 2 * 64 * 256 + n;
    prep_all<<<(total + 255) / 256, 256, 0, stream>>>(x, W1, Ws1, W2, Ws2, W3,
                                                      xb, W1t, Ws1t, W2t, Ws2t, W3t,
                                                      cnt, n);
  }

  // ---- CSR build (real edges only; XCD-chunked by dst range) ----
  count_edges<<<2048, 256, 0, stream>>>(ei, E, cnt, n);
  scan_block<<<NB, 256, 0, stream>>>(cnt, rp, bsums, n);
  scan_tops<<<1, 256, 0, stream>>>(bsums, boffs, NB);
  scan_add<<<NB, 256, 0, stream>>>(rp, boffs, cnt, n, E);   // + cursor zero
  fill_edges<<<2048, 256, 0, stream>>>(ei, E, rp, cnt, csr, n);

  const int wgrid = (n * 64 + 255) / 256;   // one wave per node
  const int egrid = (n * 256 / 4 + 255) / 256;

  // ---- layer 1: x[128] -> GAT(4x64)+AL + x_init, fused ----
  gemm_gat_fused<128, 4, 4><<<512, 512, 0, stream>>>(
      xb, W1t, Ws1t, as1, ad1, bs1, Hb, als, ald, Bv, n);
  gat_aggregate<4, 256, true><<<wgrid, 256, 0, stream>>>(Hb, als, ald, rp, csr, b1,
                                                         nullptr, Cv, n);
  bn_stats<<<NSTATB, 256, 0, stream>>>(Cv, partial, n);
  bn_finalize<<<1, 512, 0, stream>>>(partial, g1, bb1, scsh, n);
  bn_apply_elu<<<egrid, 256, 0, stream>>>(Cv, scsh, Bv, hb, n * 256);   // h1 -> hb

  // ---- layer 2: h1 -> GAT(4x64)+AL + x_skip, fused ----
  gemm_gat_fused<256, 4, 1><<<512, 320, 0, stream>>>(
      hb, W2t, Ws2t, as2, ad2, bs2, Hb, als, ald, D, n);
  gat_aggregate<4, 256, true><<<wgrid, 256, 0, stream>>>(Hb, als, ald, rp, csr, b2,
                                                         nullptr, Cv, n);
  bn_stats<<<NSTATB, 256, 0, stream>>>(Cv, partial, n);
  bn_finalize<<<1, 512, 0, stream>>>(partial, g2, bb2, scsh, n);
  bn_apply_elu<<<egrid, 256, 0, stream>>>(Cv, scsh, nullptr, hb, n * 256); // h2 -> hb

  // ---- layer 3: heads=1, mean(=identity), + b3 + x_skip -> d_out ----
  gemm_gat3<<<512, 256, 0, stream>>>(hb, W3t, as3, ad3, Hb, als, ald, n);
  gat_aggregate<1, 64, false><<<wgrid, 256, 0, stream>>>(Hb, als, ald, rp, csr, b3, D,
                                                         d_out, n);
}

// Round 17
// 415.697 us; speedup vs baseline: 1.3367x; 1.0640x over previous
//
#include <hip/hip_runtime.h>
#include <hip/hip_bf16.h>
#include <cstdint>
#include <cstddef>

// ---------------------------------------------------------------------------
// GATWithSkip: 3x GATConv + BN/ELU/skips on MI355X.
// R16 (442us, BEST, reproduced): vectorized bn_stats; R10 aggregate/GEMM/CSR.
// R17: SINGLE change — GEMM epilogue in-wave LDS transpose so C-writes are
//      2x global_store_b128 per lane (8 dense 128B rows per instr) instead of
//      16 scalar 2B stores scattering 32B segments. GAT+skip waves + gemm3.
// ---------------------------------------------------------------------------

#define LRELU_SLOPE 0.2f
#define NSTATB 256   // bn_stats blocks (= partial rows)

typedef __attribute__((ext_vector_type(8))) short short8;   // 8 bf16 (4 VGPRs)
typedef __attribute__((ext_vector_type(4))) float f32x4;

__device__ __forceinline__ float bf2f(unsigned short u) {
  union { unsigned int i; float f; } t; t.i = ((unsigned int)u) << 16; return t.f;
}
__device__ __forceinline__ unsigned short f2bf(float f) {
  __hip_bfloat16 h = __float2bfloat16(f);   // RNE hardware convert
  return *reinterpret_cast<unsigned short*>(&h);
}

// ---------------- fused GEMM (+AL epilogue), XCD-chunked ----------------
// A bf16 [M][K]. BtH bf16 [WAVES_GAT*64][K]; BtS bf16 [WAVES_SKIP*64][K].
// Each wave owns 64 cols, B panel register-resident; all waves share tile t.
// blockIdx&7 = XCD -> contiguous tile chunk (A slice ~3.2MB, L2-resident).
// Mapping (m89): A row=lane&15, k=(lane>>4)*8+j; B col=lane&15;
// D col=lane&15, row=(lane>>4)*4+reg.
// Epilogue: stage 16x64 bf16 tile in LDS (wave-local, stride 72 for 16B
// alignment + bank spread), then 2x b128 dense row stores per lane.
template<int K, int WAVES_GAT, int WAVES_SKIP>
__global__ __launch_bounds__((WAVES_GAT + WAVES_SKIP) * 64)
void gemm_gat_fused(const unsigned short* __restrict__ A,
                    const unsigned short* __restrict__ BtH,
                    const unsigned short* __restrict__ BtS,
                    const float* __restrict__ a_s, const float* __restrict__ a_d,
                    const float* __restrict__ biasS,
                    unsigned short* __restrict__ Hout,
                    float* __restrict__ als, float* __restrict__ ald,
                    unsigned short* __restrict__ Sout, int M) {
  constexpr int NKS = K / 32;
  constexpr int NH  = WAVES_GAT * 64;
  constexpr int NS  = WAVES_SKIP * 64;
  constexpr int NW  = WAVES_GAT + WAVES_SKIP;
  __shared__ __align__(16) unsigned short trp[NW][16][72];
  const int wid  = threadIdx.x >> 6;
  const int lane = threadIdx.x & 63;
  const int r    = lane & 15;
  const int q    = lane >> 4;
  const int koff = q * 8;
  const bool isGat = wid < WAVES_GAT;
  const int colbase = isGat ? wid * 64 : (wid - WAVES_GAT) * 64;
  const unsigned short* Bt = isGat ? BtH : BtS;

  short8 b[4][NKS];
  #pragma unroll
  for (int nf = 0; nf < 4; ++nf)
    #pragma unroll
    for (int ks = 0; ks < NKS; ++ks)
      b[nf][ks] = *(const short8*)(Bt + (size_t)(colbase + nf * 16 + r) * K + ks * 32 + koff);

  float as4[4] = {}, ad4[4] = {};
  float bs4[4] = {};
  if (isGat) {
    #pragma unroll
    for (int nf = 0; nf < 4; ++nf) {
      as4[nf] = a_s[colbase + nf * 16 + r];
      ad4[nf] = a_d[colbase + nf * 16 + r];
    }
  } else {
    #pragma unroll
    for (int nf = 0; nf < 4; ++nf) bs4[nf] = biasS[colbase + nf * 16 + r];
  }

  const int lr = lane >> 3;        // store-phase: row within half-tile (0..7)
  const int lc = (lane & 7) * 8;   // store-phase: col start (0,8,..,56)

  const int ntiles = (M + 15) >> 4;
  const int chunk = (ntiles + 7) >> 3;
  const int xcd   = blockIdx.x & 7;
  const int lo    = xcd * chunk;
  const int hi    = min(lo + chunk, ntiles);
  const int bstep = gridDim.x >> 3;
  for (int t = lo + (blockIdx.x >> 3); t < hi; t += bstep) {
    const int row = t * 16 + r;
    short8 a[NKS];
    #pragma unroll
    for (int ks = 0; ks < NKS; ++ks) {
      a[ks] = (short8)(short)0;
      if (row < M) a[ks] = *(const short8*)(A + (size_t)row * K + ks * 32 + koff);
    }
    f32x4 acc[4];
    #pragma unroll
    for (int nf = 0; nf < 4; ++nf) acc[nf] = (f32x4)0.0f;
    #pragma unroll
    for (int ks = 0; ks < NKS; ++ks)
      #pragma unroll
      for (int nf = 0; nf < 4; ++nf)
        acc[nf] = __builtin_amdgcn_mfma_f32_16x16x32_bf16(a[ks], b[nf][ks], acc[nf], 0, 0, 0);

    const int rbase = t * 16 + q * 4;
    if (isGat) {
      // AL quad-reduce (uses acc in fragment layout)
      #pragma unroll
      for (int i = 0; i < 4; ++i) {
        float s = 0.f, d = 0.f;
        #pragma unroll
        for (int nf = 0; nf < 4; ++nf) {
          s = fmaf(acc[nf][i], as4[nf], s);
          d = fmaf(acc[nf][i], ad4[nf], d);
        }
        #pragma unroll
        for (int m = 8; m >= 1; m >>= 1) {
          s += __shfl_xor(s, m, 64);
          d += __shfl_xor(d, m, 64);
        }
        const int rr = rbase + i;
        if (r == 0 && rr < M) {
          als[(size_t)rr * WAVES_GAT + wid] = s;
          ald[(size_t)rr * WAVES_GAT + wid] = d;
        }
      }
      // stage tile to LDS (wave-synchronous; no barrier needed)
      #pragma unroll
      for (int nf = 0; nf < 4; ++nf)
        #pragma unroll
        for (int i = 0; i < 4; ++i)
          trp[wid][q * 4 + i][nf * 16 + r] = f2bf(acc[nf][i]);
      // dense row stores: 2 x b128 per lane (8 full 128B rows per instr)
      #pragma unroll
      for (int h = 0; h < 2; ++h) {
        const int grow = t * 16 + lr + h * 8;
        if (grow < M) {
          short8 v = *(const short8*)&trp[wid][lr + h * 8][lc];
          *(short8*)(Hout + (size_t)grow * NH + colbase + lc) = v;
        }
      }
    } else {
      #pragma unroll
      for (int nf = 0; nf < 4; ++nf)
        #pragma unroll
        for (int i = 0; i < 4; ++i)
          trp[wid][q * 4 + i][nf * 16 + r] = f2bf(acc[nf][i] + bs4[nf]);
      #pragma unroll
      for (int h = 0; h < 2; ++h) {
        const int grow = t * 16 + lr + h * 8;
        if (grow < M) {
          short8 v = *(const short8*)&trp[wid][lr + h * 8][lc];
          *(short8*)(Sout + (size_t)grow * NS + colbase + lc) = v;
        }
      }
    }
  }
}

// ---------------- layer-3 GEMM (64 cols, heads=1) + AL, XCD-chunked --------
__global__ __launch_bounds__(256)
void gemm_gat3(const unsigned short* __restrict__ A, const unsigned short* __restrict__ Bt,
               const float* __restrict__ a_s, const float* __restrict__ a_d,
               unsigned short* __restrict__ Hout, float* __restrict__ als,
               float* __restrict__ ald, int M) {
  constexpr int K = 256, NKS = 8;
  __shared__ __align__(16) unsigned short trp[4][16][72];
  const int wid  = threadIdx.x >> 6;
  const int lane = threadIdx.x & 63;
  const int r    = lane & 15;
  const int q    = lane >> 4;
  const int koff = q * 8;

  short8 b[4][NKS];
  #pragma unroll
  for (int nf = 0; nf < 4; ++nf)
    #pragma unroll
    for (int ks = 0; ks < NKS; ++ks)
      b[nf][ks] = *(const short8*)(Bt + (size_t)(nf * 16 + r) * K + ks * 32 + koff);
  float as4[4], ad4[4];
  #pragma unroll
  for (int nf = 0; nf < 4; ++nf) {
    as4[nf] = a_s[nf * 16 + r];
    ad4[nf] = a_d[nf * 16 + r];
  }

  const int lr = lane >> 3;
  const int lc = (lane & 7) * 8;

  const int ntiles = (M + 15) >> 4;
  const int chunk = (ntiles + 7) >> 3;
  const int xcd   = blockIdx.x & 7;
  const int lo    = xcd * chunk;
  const int hi    = min(lo + chunk, ntiles);
  const int bstep = (gridDim.x >> 3) * 4;
  for (int t = lo + (blockIdx.x >> 3) * 4 + wid; t < hi; t += bstep) {
    const int row = t * 16 + r;
    short8 a[NKS];
    #pragma unroll
    for (int ks = 0; ks < NKS; ++ks) {
      a[ks] = (short8)(short)0;
      if (row < M) a[ks] = *(const short8*)(A + (size_t)row * K + ks * 32 + koff);
    }
    f32x4 acc[4];
    #pragma unroll
    for (int nf = 0; nf < 4; ++nf) acc[nf] = (f32x4)0.0f;
    #pragma unroll
    for (int ks = 0; ks < NKS; ++ks)
      #pragma unroll
      for (int nf = 0; nf < 4; ++nf)
        acc[nf] = __builtin_amdgcn_mfma_f32_16x16x32_bf16(a[ks], b[nf][ks], acc[nf], 0, 0, 0);

    const int rbase = t * 16 + q * 4;
    #pragma unroll
    for (int i = 0; i < 4; ++i) {
      float s = 0.f, d = 0.f;
      #pragma unroll
      for (int nf = 0; nf < 4; ++nf) {
        s = fmaf(acc[nf][i], as4[nf], s);
        d = fmaf(acc[nf][i], ad4[nf], d);
      }
      #pragma unroll
      for (int m = 8; m >= 1; m >>= 1) {
        s += __shfl_xor(s, m, 64);
        d += __shfl_xor(d, m, 64);
      }
      const int rr = rbase + i;
      if (r == 0 && rr < M) { als[rr] = s; ald[rr] = d; }
    }
    // staged dense stores
    #pragma unroll
    for (int nf = 0; nf < 4; ++nf)
      #pragma unroll
      for (int i = 0; i < 4; ++i)
        trp[wid][q * 4 + i][nf * 16 + r] = f2bf(acc[nf][i]);
    #pragma unroll
    for (int h = 0; h < 2; ++h) {
      const int grow = t * 16 + lr + h * 8;
      if (grow < M) {
        short8 v = *(const short8*)&trp[wid][lr + h * 8][lc];
        *(short8*)(Hout + (size_t)grow * 64 + lc) = v;
      }
    }
  }
}

// ---- one-shot prep: x->bf16 + 5 weight transposes + zero cnt ----
__global__ __launch_bounds__(256)
void prep_all(const float* __restrict__ x,
              const float* __restrict__ W1, const float* __restrict__ Ws1,
              const float* __restrict__ W2, const float* __restrict__ Ws2,
              const float* __restrict__ W3,
              unsigned short* __restrict__ xb,
              unsigned short* __restrict__ W1t, unsigned short* __restrict__ Ws1t,
              unsigned short* __restrict__ W2t, unsigned short* __restrict__ Ws2t,
              unsigned short* __restrict__ W3t,
              int* __restrict__ cnt, int n) {
  int idx = blockIdx.x * blockDim.x + threadIdx.x;
  const int nx = n * 32;            // n*128/4 float4 groups
  if (idx < nx) {
    float4 v = ((const float4*)x)[idx];
    ushort4 o;
    o.x = f2bf(v.x); o.y = f2bf(v.y); o.z = f2bf(v.z); o.w = f2bf(v.w);
    ((ushort4*)xb)[idx] = o;
    return;
  }
  idx -= nx;
  if (idx < 256 * 128) { int nn = idx >> 7, kk = idx & 127; W1t[idx]  = f2bf(W1[kk * 256 + nn]);  return; }
  idx -= 256 * 128;
  if (idx < 256 * 128) { int nn = idx >> 7, kk = idx & 127; Ws1t[idx] = f2bf(Ws1[kk * 256 + nn]); return; }
  idx -= 256 * 128;
  if (idx < 256 * 256) { int nn = idx >> 8, kk = idx & 255; W2t[idx]  = f2bf(W2[kk * 256 + nn]);  return; }
  idx -= 256 * 256;
  if (idx < 64 * 256)  { int nn = idx >> 8, kk = idx & 255; Ws2t[idx] = f2bf(Ws2[kk * 64 + nn]);  return; }
  idx -= 64 * 256;
  if (idx < 64 * 256)  { int nn = idx >> 8, kk = idx & 255; W3t[idx]  = f2bf(W3[kk * 64 + nn]); return; }
  idx -= 64 * 256;
  if (idx < n) cnt[idx] = 0;        // count array zero (replaces memset)
}

// ---------------- CSR build (dst-keyed, XCD-chunked by dst range) ----------
__global__ void count_edges(const int* __restrict__ ei, int E, int* __restrict__ counts,
                            int n) {
  const int g = blockIdx.x & 7;
  const int chunk = (n + 7) >> 3;
  const int lo = g * chunk, hi = min(lo + chunk, n);
  const int stride = (gridDim.x >> 3) * blockDim.x;
  for (int i = (blockIdx.x >> 3) * blockDim.x + threadIdx.x; i < E; i += stride) {
    int d = ei[E + i];
    if (d >= lo && d < hi) atomicAdd(&counts[d], 1);
  }
}
__global__ void scan_block(const int* __restrict__ in, int* __restrict__ out,
                           int* __restrict__ bsums, int n) {
  __shared__ int tmp[256];
  int t = threadIdx.x;
  int gid = blockIdx.x * 256 + t;
  int v = (gid < n) ? in[gid] : 0;
  tmp[t] = v;
  __syncthreads();
  #pragma unroll
  for (int off = 1; off < 256; off <<= 1) {
    int x = (t >= off) ? tmp[t - off] : 0;
    __syncthreads();
    tmp[t] += x;
    __syncthreads();
  }
  if (gid < n) out[gid] = tmp[t] - v;
  if (t == 255) bsums[blockIdx.x] = tmp[255];
}
__global__ void scan_tops(const int* __restrict__ bsums, int* __restrict__ boffs, int nb) {
  __shared__ int tmp[256];
  int t = threadIdx.x;
  int v = (t < nb) ? bsums[t] : 0;
  tmp[t] = v;
  __syncthreads();
  #pragma unroll
  for (int off = 1; off < 256; off <<= 1) {
    int x = (t >= off) ? tmp[t - off] : 0;
    __syncthreads();
    tmp[t] += x;
    __syncthreads();
  }
  if (t < nb) boffs[t] = tmp[t] - v;
}
// also zeros cnt (cursor for fill_edges) — removes a memset dispatch
__global__ void scan_add(int* __restrict__ rp, const int* __restrict__ boffs,
                         int* __restrict__ cnt, int n, int etot) {
  int gid = blockIdx.x * 256 + threadIdx.x;
  if (gid < n) {
    rp[gid] += boffs[blockIdx.x];
    cnt[gid] = 0;
  }
  if (gid == 0) rp[n] = etot;
}
__global__ void fill_edges(const int* __restrict__ ei, int E, const int* __restrict__ rp,
                           int* __restrict__ cursor, int* __restrict__ csr, int n) {
  const int g = blockIdx.x & 7;
  const int chunk = (n + 7) >> 3;
  const int lo = g * chunk, hi = min(lo + chunk, n);
  const int stride = (gridDim.x >> 3) * blockDim.x;
  for (int i = (blockIdx.x >> 3) * blockDim.x + threadIdx.x; i < E; i += stride) {
    int d = ei[E + i];
    if (d >= lo && d < hi) {
      int pos = rp[d] + atomicAdd(&cursor[d], 1);
      csr[pos] = ei[i];
    }
  }
}

// ---------------- wave-per-node segment-softmax aggregation (bf16 H) --------
// One wave per node (full TLP); lane owns CPL contiguous channels; per-lane
// att (independent exp chains). Self-loop inline. No segment-max (logits
// bounded; softmax shift-invariant). R10-proven body, untouched.
template<int HEADS, int HCt, bool OUT_BF16>
__global__ __launch_bounds__(256)
void gat_aggregate(const unsigned short* __restrict__ H, const float* __restrict__ als,
                   const float* __restrict__ ald, const int* __restrict__ rp,
                   const int* __restrict__ csr, const float* __restrict__ bias,
                   const unsigned short* __restrict__ skip, void* __restrict__ out, int n) {
  constexpr int CPL = HCt / 64;
  int w = (blockIdx.x * blockDim.x + threadIdx.x) >> 6;
  int lane = threadIdx.x & 63;
  if (w >= n) return;
  const int beg = rp[w], end = rp[w + 1];
  const int myhead = (HEADS == 1) ? 0 : (lane >> 4);
  const float adh = ald[(size_t)w * HEADS + myhead];

  auto att = [&](int s) -> float {
    float e = als[(size_t)s * HEADS + myhead] + adh;
    e = fmaxf(e, LRELU_SLOPE * e);
    return __expf(e);
  };

  // self-loop term
  float acc[CPL];
  float ssum = att(w);
  {
    const unsigned short* hp = H + (size_t)w * HCt + lane * CPL;
    if constexpr (CPL == 4) {
      ushort4 hv = *(const ushort4*)hp;
      acc[0] = ssum * bf2f(hv.x); acc[1] = ssum * bf2f(hv.y);
      acc[2] = ssum * bf2f(hv.z); acc[3] = ssum * bf2f(hv.w);
    } else {
      acc[0] = ssum * bf2f(hp[0]);
    }
  }

  int j = beg;
  for (; j + 8 <= end; j += 8) {
    int sidx[8];
    #pragma unroll
    for (int u = 0; u < 8; ++u) sidx[u] = csr[j + u];
    if constexpr (CPL == 4) {
      ushort4 hv[8];
      #pragma unroll
      for (int u = 0; u < 8; ++u)
        hv[u] = *(const ushort4*)(H + (size_t)sidx[u] * HCt + lane * 4);
      float ex[8];
      #pragma unroll
      for (int u = 0; u < 8; ++u) ex[u] = att(sidx[u]);
      #pragma unroll
      for (int u = 0; u < 8; ++u) {
        ssum += ex[u];
        acc[0] = fmaf(ex[u], bf2f(hv[u].x), acc[0]);
        acc[1] = fmaf(ex[u], bf2f(hv[u].y), acc[1]);
        acc[2] = fmaf(ex[u], bf2f(hv[u].z), acc[2]);
        acc[3] = fmaf(ex[u], bf2f(hv[u].w), acc[3]);
      }
    } else {
      unsigned short hv[8];
      #pragma unroll
      for (int u = 0; u < 8; ++u) hv[u] = H[(size_t)sidx[u] * HCt + lane];
      float ex[8];
      #pragma unroll
      for (int u = 0; u < 8; ++u) ex[u] = att(sidx[u]);
      #pragma unroll
      for (int u = 0; u < 8; ++u) {
        ssum += ex[u];
        acc[0] = fmaf(ex[u], bf2f(hv[u]), acc[0]);
      }
    }
  }
  for (; j + 4 <= end; j += 4) {
    int sidx[4];
    #pragma unroll
    for (int u = 0; u < 4; ++u) sidx[u] = csr[j + u];
    float ex[4];
    #pragma unroll
    for (int u = 0; u < 4; ++u) ex[u] = att(sidx[u]);
    if constexpr (CPL == 4) {
      ushort4 hv[4];
      #pragma unroll
      for (int u = 0; u < 4; ++u)
        hv[u] = *(const ushort4*)(H + (size_t)sidx[u] * HCt + lane * 4);
      #pragma unroll
      for (int u = 0; u < 4; ++u) {
        ssum += ex[u];
        acc[0] = fmaf(ex[u], bf2f(hv[u].x), acc[0]);
        acc[1] = fmaf(ex[u], bf2f(hv[u].y), acc[1]);
        acc[2] = fmaf(ex[u], bf2f(hv[u].z), acc[2]);
        acc[3] = fmaf(ex[u], bf2f(hv[u].w), acc[3]);
      }
    } else {
      unsigned short hv[4];
      #pragma unroll
      for (int u = 0; u < 4; ++u) hv[u] = H[(size_t)sidx[u] * HCt + lane];
      #pragma unroll
      for (int u = 0; u < 4; ++u) {
        ssum += ex[u];
        acc[0] = fmaf(ex[u], bf2f(hv[u]), acc[0]);
      }
    }
  }
  for (; j < end; ++j) {
    const int s = csr[j];
    const float ex = att(s);
    ssum += ex;
    const unsigned short* hp = H + (size_t)s * HCt + lane * CPL;
    if constexpr (CPL == 4) {
      ushort4 hv = *(const ushort4*)hp;
      acc[0] = fmaf(ex, bf2f(hv.x), acc[0]);
      acc[1] = fmaf(ex, bf2f(hv.y), acc[1]);
      acc[2] = fmaf(ex, bf2f(hv.z), acc[2]);
      acc[3] = fmaf(ex, bf2f(hv.w), acc[3]);
    } else {
      acc[0] = fmaf(ex, bf2f(hp[0]), acc[0]);
    }
  }

  const float inv = 1.f / (ssum + 1e-16f);
  #pragma unroll
  for (int c = 0; c < CPL; ++c) {
    int ch = lane * CPL + c;
    float v = acc[c] * inv + bias[ch];
    if (skip) v += bf2f(skip[(size_t)w * HCt + ch]);
    if constexpr (OUT_BF16)
      ((unsigned short*)out)[(size_t)w * HCt + ch] = f2bf(v);
    else
      ((float*)out)[(size_t)w * HCt + ch] = v;
  }
}

// ---------------- batch norm stats (vectorized, no global atomics) ----------
__global__ __launch_bounds__(256)
void bn_stats(const unsigned short* __restrict__ X, float* __restrict__ partial, int n) {
  const int lane = threadIdx.x & 63;
  const int rg   = threadIdx.x >> 6;     // 0..3 row groups
  const int c4   = lane * 4;
  float s0 = 0.f, s1 = 0.f, s2 = 0.f, s3 = 0.f;
  float q0 = 0.f, q1 = 0.f, q2 = 0.f, q3 = 0.f;
  const int step = NSTATB * 4;
  int r = blockIdx.x * 4 + rg;
  for (; r + 3 * step < n; r += 4 * step) {
    #pragma unroll
    for (int u = 0; u < 4; ++u) {
      ushort4 v = *(const ushort4*)(X + (size_t)(r + u * step) * 256 + c4);
      float f0 = bf2f(v.x), f1 = bf2f(v.y), f2 = bf2f(v.z), f3 = bf2f(v.w);
      s0 += f0; s1 += f1; s2 += f2; s3 += f3;
      q0 = fmaf(f0, f0, q0); q1 = fmaf(f1, f1, q1);
      q2 = fmaf(f2, f2, q2); q3 = fmaf(f3, f3, q3);
    }
  }
  for (; r < n; r += step) {
    ushort4 v = *(const ushort4*)(X + (size_t)r * 256 + c4);
    float f0 = bf2f(v.x), f1 = bf2f(v.y), f2 = bf2f(v.z), f3 = bf2f(v.w);
    s0 += f0; s1 += f1; s2 += f2; s3 += f3;
    q0 = fmaf(f0, f0, q0); q1 = fmaf(f1, f1, q1);
    q2 = fmaf(f2, f2, q2); q3 = fmaf(f3, f3, q3);
  }
  __shared__ float red[512];
  red[threadIdx.x] = 0.f;
  red[256 + threadIdx.x] = 0.f;
  __syncthreads();
  atomicAdd(&red[c4 + 0], s0); atomicAdd(&red[c4 + 1], s1);
  atomicAdd(&red[c4 + 2], s2); atomicAdd(&red[c4 + 3], s3);
  atomicAdd(&red[256 + c4 + 0], q0); atomicAdd(&red[256 + c4 + 1], q1);
  atomicAdd(&red[256 + c4 + 2], q2); atomicAdd(&red[256 + c4 + 3], q3);
  __syncthreads();
  partial[(size_t)blockIdx.x * 512 + threadIdx.x] = red[threadIdx.x];
  partial[(size_t)blockIdx.x * 512 + 256 + threadIdx.x] = red[256 + threadIdx.x];
}
// reduce NSTATB partial rows; threads 0-255 own sums, 256-511 own sumsqs
__global__ __launch_bounds__(512)
void bn_finalize(const float* __restrict__ partial, const float* __restrict__ gamma,
                 const float* __restrict__ beta, float* __restrict__ scsh, int n) {
  __shared__ float sq[512];
  const int t = threadIdx.x;
  float acc = 0.f;
  #pragma unroll 8
  for (int r = 0; r < NSTATB; ++r) acc += partial[(size_t)r * 512 + t];
  sq[t] = acc;
  __syncthreads();
  if (t < 256) {
    float mean = sq[t] / (float)n;
    float var = sq[256 + t] / (float)n - mean * mean;
    float sc = gamma[t] * rsqrtf(var + 1e-5f);
    scsh[t] = sc;
    scsh[256 + t] = beta[t] - mean * sc;
  }
}
// BN affine + ELU (+bf16 skip) -> bf16 (all node-major)
__global__ __launch_bounds__(256)
void bn_apply_elu(const unsigned short* __restrict__ X, const float* __restrict__ scsh,
                  const unsigned short* __restrict__ skip, unsigned short* __restrict__ Y,
                  int total) {
  int i4 = blockIdx.x * blockDim.x + threadIdx.x;
  if (i4 * 4 >= total) return;
  ushort4 xv = ((const ushort4*)X)[i4];
  int cb = (i4 * 4) & 255;
  float4 sc = *(const float4*)(scsh + cb);
  float4 sh = *(const float4*)(scsh + 256 + cb);
  float4 y;
  y.x = fmaf(bf2f(xv.x), sc.x, sh.x);
  y.y = fmaf(bf2f(xv.y), sc.y, sh.y);
  y.z = fmaf(bf2f(xv.z), sc.z, sh.z);
  y.w = fmaf(bf2f(xv.w), sc.w, sh.w);
  y.x = (y.x > 0.f) ? y.x : expm1f(y.x);
  y.y = (y.y > 0.f) ? y.y : expm1f(y.y);
  y.z = (y.z > 0.f) ? y.z : expm1f(y.z);
  y.w = (y.w > 0.f) ? y.w : expm1f(y.w);
  if (skip) {
    ushort4 s4 = ((const ushort4*)skip)[i4];
    y.x += bf2f(s4.x); y.y += bf2f(s4.y); y.z += bf2f(s4.z); y.w += bf2f(s4.w);
  }
  ushort4 o;
  o.x = f2bf(y.x); o.y = f2bf(y.y); o.z = f2bf(y.z); o.w = f2bf(y.w);
  ((ushort4*)Y)[i4] = o;
}

// ---------------------------------------------------------------------------
extern "C" void kernel_launch(void* const* d_in, const int* in_sizes, int n_in,
                              void* d_out, int out_size, void* d_ws, size_t ws_size,
                              hipStream_t stream) {
  const float* x   = (const float*)d_in[0];
  const int*   ei  = (const int*)d_in[1];
  const float* W1  = (const float*)d_in[2];
  const float* as1 = (const float*)d_in[3];
  const float* ad1 = (const float*)d_in[4];
  const float* b1  = (const float*)d_in[5];
  const float* g1  = (const float*)d_in[6];
  const float* bb1 = (const float*)d_in[7];
  const float* W2  = (const float*)d_in[8];
  const float* as2 = (const float*)d_in[9];
  const float* ad2 = (const float*)d_in[10];
  const float* b2  = (const float*)d_in[11];
  const float* g2  = (const float*)d_in[12];
  const float* bb2 = (const float*)d_in[13];
  const float* W3  = (const float*)d_in[14];
  const float* as3 = (const float*)d_in[15];
  const float* ad3 = (const float*)d_in[16];
  const float* b3  = (const float*)d_in[17];
  const float* Ws1 = (const float*)d_in[18];
  const float* bs1 = (const float*)d_in[19];
  const float* Ws2 = (const float*)d_in[20];
  const float* bs2 = (const float*)d_in[21];

  const int n = in_sizes[0] / 128;   // 50000
  const int E = in_sizes[1] / 2;     // 800000

  char* wsp = (char*)d_ws;
  auto carve = [&](size_t bytes) -> void* {
    void* p = (void*)wsp;
    wsp += (bytes + 255) & ~(size_t)255;
    return p;
  };
  unsigned short* Hb  = (unsigned short*)carve((size_t)n * 256 * 2);  // GEMM out (node-major)
  unsigned short* hb  = (unsigned short*)carve((size_t)n * 256 * 2);  // BN/ELU out
  unsigned short* xbD = (unsigned short*)carve((size_t)n * 128 * 2);  // xb, then D
  unsigned short* xb  = xbD;
  unsigned short* D   = xbD;            // x_skip (bf16, n*64); written after xb dead
  unsigned short* Bv  = (unsigned short*)carve((size_t)n * 256 * 2);  // x_init
  unsigned short* Cv  = (unsigned short*)carve((size_t)n * 256 * 2);  // aggregate out
  float* als  = (float*)carve((size_t)n * 4 * 4);
  float* ald  = (float*)carve((size_t)n * 4 * 4);
  int*   rp   = (int*)carve((size_t)(n + 1) * 4);
  int*   cnt  = (int*)carve((size_t)n * 4);
  int*   bsums= (int*)carve(256 * 4);
  int*   boffs= (int*)carve(256 * 4);
  int*   csr  = (int*)carve((size_t)E * 4);
  float* partial = (float*)carve((size_t)NSTATB * 512 * 4);  // BN partials
  float* scsh = (float*)carve(512 * 4);
  unsigned short* W1t  = (unsigned short*)carve(128 * 256 * 2);
  unsigned short* Ws1t = (unsigned short*)carve(128 * 256 * 2);
  unsigned short* W2t  = (unsigned short*)carve(256 * 256 * 2);
  unsigned short* Ws2t = (unsigned short*)carve(256 * 64 * 2);
  unsigned short* W3t  = (unsigned short*)carve(256 * 64 * 2);

  const int NB = (n + 255) / 256;

  // ---- prep first: conversions + cnt zero (no memsets) ----
  {
    const int total = n * 32 + 2 * 256 * 128 + 256 * 256 + 2 * 64 * 256 + n;
    prep_all<<<(total + 255) / 256, 256, 0, stream>>>(x, W1, Ws1, W2, Ws2, W3,
                                                      xb, W1t, Ws1t, W2t, Ws2t, W3t,
                                                      cnt, n);
  }

  // ---- CSR build (real edges only; XCD-chunked by dst range) ----
  count_edges<<<2048, 256, 0, stream>>>(ei, E, cnt, n);
  scan_block<<<NB, 256, 0, stream>>>(cnt, rp, bsums, n);
  scan_tops<<<1, 256, 0, stream>>>(bsums, boffs, NB);
  scan_add<<<NB, 256, 0, stream>>>(rp, boffs, cnt, n, E);   // + cursor zero
  fill_edges<<<2048, 256, 0, stream>>>(ei, E, rp, cnt, csr, n);

  const int wgrid = (n * 64 + 255) / 256;   // one wave per node
  const int egrid = (n * 256 / 4 + 255) / 256;

  // ---- layer 1: x[128] -> GAT(4x64)+AL + x_init, fused ----
  gemm_gat_fused<128, 4, 4><<<512, 512, 0, stream>>>(
      xb, W1t, Ws1t, as1, ad1, bs1, Hb, als, ald, Bv, n);
  gat_aggregate<4, 256, true><<<wgrid, 256, 0, stream>>>(Hb, als, ald, rp, csr, b1,
                                                         nullptr, Cv, n);
  bn_stats<<<NSTATB, 256, 0, stream>>>(Cv, partial, n);
  bn_finalize<<<1, 512, 0, stream>>>(partial, g1, bb1, scsh, n);
  bn_apply_elu<<<egrid, 256, 0, stream>>>(Cv, scsh, Bv, hb, n * 256);   // h1 -> hb

  // ---- layer 2: h1 -> GAT(4x64)+AL + x_skip, fused ----
  gemm_gat_fused<256, 4, 1><<<512, 320, 0, stream>>>(
      hb, W2t, Ws2t, as2, ad2, bs2, Hb, als, ald, D, n);
  gat_aggregate<4, 256, true><<<wgrid, 256, 0, stream>>>(Hb, als, ald, rp, csr, b2,
                                                         nullptr, Cv, n);
  bn_stats<<<NSTATB, 256, 0, stream>>>(Cv, partial, n);
  bn_finalize<<<1, 512, 0, stream>>>(partial, g2, bb2, scsh, n);
  bn_apply_elu<<<egrid, 256, 0, stream>>>(Cv, scsh, nullptr, hb, n * 256); // h2 -> hb

  // ---- layer 3: heads=1, mean(=identity), + b3 + x_skip -> d_out ----
  gemm_gat3<<<512, 256, 0, stream>>>(hb, W3t, as3, ad3, Hb, als, ald, n);
  gat_aggregate<1, 64, false><<<wgrid, 256, 0, stream>>>(Hb, als, ald, rp, csr, b3, D,
                                                         d_out, n);
}